// Round 5
// baseline (1104.772 us; speedup 1.0000x reference)
//
#include <hip/hip_runtime.h>

#define TOK 8192   // B*S
#define DIM 512    // D
#define NE  32     // experts
#define KTOT (NE * DIM)

#define BM 256
#define BN 128
#define BK 64

typedef float f32x4  __attribute__((ext_vector_type(4)));
typedef float f32x16 __attribute__((ext_vector_type(16)));
typedef short s16x8  __attribute__((ext_vector_type(8)));

typedef const void __attribute__((address_space(1)))* gp1_t;
typedef void __attribute__((address_space(3)))* lp3_t;

__device__ __forceinline__ void gl_lds16(const void* g, void* l) {
    __builtin_amdgcn_global_load_lds((gp1_t)g, (lp3_t)l, 16, 0, 0);
}

// A tile: 256 rows x 128B = 32KB; 512 thr x 16B = 8KB/round -> 4 rounds (4 vmem ops/wave)
__device__ __forceinline__ void stageA(const ushort* g, char* l) {
#pragma unroll
    for (int r = 0; r < 4; ++r)
        gl_lds16(g + (size_t)r * 64 * DIM, l + r * 8192);
}
// B tile: 128 rows x 128B = 16KB -> 2 rounds (2 vmem ops/wave)
__device__ __forceinline__ void stageB(const ushort* g, char* l) {
    gl_lds16(g, l);
    gl_lds16(g + (size_t)64 * KTOT, l + 8192);
}

// counted-vmcnt publish: wait own DMA down to N outstanding, then barrier.
// sched_barrier stops any LDS read being hoisted above the publish point.
template<int N>
__device__ __forceinline__ void wait_bar() {
    asm volatile("s_waitcnt vmcnt(%0)" :: "n"(N) : "memory");
    __builtin_amdgcn_s_barrier();
    __builtin_amdgcn_sched_barrier(0);
}

__device__ __forceinline__ ushort f2bf(float f) {
    unsigned u = __builtin_bit_cast(unsigned, f);
    unsigned r = (u + 0x7fffu + ((u >> 16) & 1u)) >> 16;
    return (ushort)r;
}

// ---- fused prep: blocks [0,2048) transpose+convert W; [2048,3072) gates+cvt x
__global__ __launch_bounds__(256) void k_prep(const float* __restrict__ w,
                                              ushort* __restrict__ wt,
                                              const float* __restrict__ x,
                                              const float* __restrict__ gw,
                                              const float* __restrict__ gb,
                                              float* __restrict__ G,
                                              ushort* __restrict__ xb) {
    __shared__ __align__(16) char smem[64 * 65 * 4];
    const int bx = blockIdx.x;
    const int tid = threadIdx.x;
    if (bx < 2048) {
        // ---- Wt[f][e*512+d] = bf16(w[e][d][f]), 64x64 tile ----
        float (*tile)[65] = (float(*)[65])smem;
        const int e = bx >> 6;
        const int f0 = ((bx >> 3) & 7) * 64;
        const int d0 = (bx & 7) * 64;
        const int tx = tid & 63, ty = tid >> 6;  // ty 0..3
        const float* we = w + (size_t)e * DIM * DIM;
#pragma unroll
        for (int i = ty; i < 64; i += 4)
            tile[i][tx] = we[(size_t)(d0 + i) * DIM + f0 + tx];
        __syncthreads();
#pragma unroll
        for (int i = ty; i < 64; i += 4)
            wt[(size_t)(f0 + i) * KTOT + e * DIM + d0 + tx] = f2bf(tile[tx][i]);
    } else {
        // ---- gates (8 tokens/block, shfl softmax) + x -> bf16 ----
        float* xs = (float*)smem;
        const int t0 = (bx - 2048) * 8;
        const float* xBase = x + (size_t)t0 * DIM;
#pragma unroll
        for (int k = 0; k < 4; ++k) {
            int i4 = (k * 256 + tid) * 4;
            float4 v = *(const float4*)(xBase + i4);
            xs[i4 + 0] = v.x; xs[i4 + 1] = v.y; xs[i4 + 2] = v.z; xs[i4 + 3] = v.w;
            ushort4 o;
            o.x = f2bf(v.x); o.y = f2bf(v.y); o.z = f2bf(v.z); o.w = f2bf(v.w);
            *(ushort4*)(xb + (size_t)t0 * DIM + i4) = o;
        }
        __syncthreads();
        const int tok = tid >> 5;   // 0..7
        const int e = tid & 31;
        float l = gb[e];
        const float* xr = xs + tok * DIM;
#pragma unroll 8
        for (int d = 0; d < DIM; ++d)
            l += xr[d] * gw[d * NE + e];
        float mx = l;
#pragma unroll
        for (int m = 16; m >= 1; m >>= 1) mx = fmaxf(mx, __shfl_xor(mx, m));
        float ex = expf(l - mx);
        float s = ex;
#pragma unroll
        for (int m = 16; m >= 1; m >>= 1) s += __shfl_xor(s, m);
        G[(size_t)(t0 + tok) * NE + e] = ex / s;
    }
}

// ---------- main GEMM v6: counted-vmcnt pipeline, static 4-slot B ring ------
// Evidence: v1/v2/v4/v5 all ~890-925 TF = the documented 2-barrier ceiling
// (matrix pipe busy only ~40%; MFMA roofline is 55us). v3 (counted vmcnt
// WITHOUT fine interleave, rotating pointers) regressed exactly as m196
// predicts. v6 = faithful T3+T4+T5:
//  - B: 4-slot ring (4x16KB), slot = ee&3 (compile-time via unroll 4),
//    staged TWO ahead; one barrier per g, preceded by uniform vmcnt(2).
//    Invariant entering g: outstanding = B(g)[2] + B(g+1)[2] (+A, older);
//    wait(2) drains B(g)+A, leaves B(g+1) in flight. vmcnt(0) only at g=127.
//  - A: single 32KB buffer; frags->regs at ee==0; restaged at ee==1 (issued
//    before B(g+2) so it is OLDER in the vmcnt stream and gets drained by
//    the next wait(2)).
//  - ds_reads are plain C++ loads (compiler emits exact lgkmcnt);
//    setprio(1) around each 8-MFMA cluster (T5).
// LDS: A 32KB + B-ring 64KB + Gs 16KB = 112KB -> 1 block/CU, 2 waves/SIMD.
// Fragments/swizzle/fold/epilogue identical to the verified v2/v5 ones.
__global__ __launch_bounds__(512, 2) void k_moe_gemm(const ushort* __restrict__ xb,
                                                     const ushort* __restrict__ wt,
                                                     const float* __restrict__ G,
                                                     float* __restrict__ out0,
                                                     float* __restrict__ out1) {
    __shared__ __align__(16) ushort As[BM * BK];      // 32 KB (single buffer)
    __shared__ __align__(16) ushort Bs[4][BN * BK];   // 4 x 16 KB ring
    __shared__ float Gs[16][BM];                      // 16 KB

    const int tid = threadIdx.x;
    const int m0 = blockIdx.y * BM;
    const int n0 = blockIdx.x * BN;
    const int e0 = blockIdx.z * 16;
    float* __restrict__ dst = blockIdx.z ? out1 : out0;

    for (int i = tid; i < 16 * BM; i += 512) {
        int e = i >> 8, r = i & 255;
        Gs[e][r] = G[(size_t)(m0 + r) * NE + e0 + e];
    }

    const int lane = tid & 63;
    const int wave = tid >> 6;          // 0..7
    const int wm = (wave & 3) * 64;     // 4 m-positions (0..192)
    const int wn = (wave >> 2) * 64;    // 2 n-positions (0,64)
    const int l31 = lane & 31;
    const int hi = lane >> 5;           // 0..1
    const int key = l31 & 7;

    // frag read offsets: row*128 + ((2s+hi) ^ (row&7))*16   (row&7 == key)
    int chunkOff[4], rowOffA[2], rowOffB[2];
#pragma unroll
    for (int s = 0; s < 4; ++s) chunkOff[s] = ((2 * s + hi) ^ key) * 16;
#pragma unroll
    for (int i = 0; i < 2; ++i) {
        rowOffA[i] = (wm + i * 32 + l31) * 128;
        rowOffB[i] = (wn + i * 32 + l31) * 128;
    }

    // staging map: 512 thr x 16B = 8KB/round = 64 rows of 128B
    const int srow = tid >> 3;                       // 0..63
    const int scol = ((tid & 7) ^ (srow & 7)) * 8;   // swizzled global column
    const ushort* aBase = xb + (size_t)(m0 + srow) * DIM + scol;
    const ushort* bBase = wt + (size_t)(n0 + srow) * KTOT + (size_t)e0 * DIM + scol;
    const int ldsOff = tid * 16;

    f32x16 zv16;
#pragma unroll
    for (int j = 0; j < 16; ++j) zv16[j] = 0.f;
    f32x16 acc[2][2];
#pragma unroll
    for (int i = 0; i < 2; ++i)
#pragma unroll
        for (int j = 0; j < 2; ++j) acc[i][j] = zv16;

    __syncthreads();   // publish Gs (lgkmcnt(0)+barrier)

    // prologue: A(0) [4 ops, oldest], B(0) [2], B(1) [2]. No drain here:
    // g=0's wait(2) leaves B(1) in flight and drains A(0)+B(0).
    stageA(aBase, (char*)As + ldsOff);
    stageB(bBase, (char*)Bs[0] + ldsOff);
    stageB(bBase + (size_t)1 * DIM, (char*)Bs[1] + ldsOff);

    s16x8 areg[2][4];

#pragma unroll 1
    for (int kt = 0; kt < 8; ++kt) {
#pragma unroll 4
        for (int ee = 0; ee < 16; ++ee) {
            const int g = kt * 16 + ee;

            // publish B(g) (and any older A); keep B(g+1) in flight
            if (kt == 7 && ee == 15) wait_bar<0>();
            else                     wait_bar<2>();

            // A restage first (older in vmcnt stream than B(g+2))
            if (ee == 1 && kt < 7)
                stageA(aBase + (kt + 1) * BK, (char*)As + ldsOff);
            // issue B two ahead into slot (ee+2)&3 (last read at g-2)
            const int gn = g + 2;
            if (gn < 128) {
                const ushort* bN = bBase + (size_t)(gn & 15) * DIM + (gn >> 4) * BK;
                stageB(bN, (char*)Bs[(ee + 2) & 3] + ldsOff);
            }

            // A fragments -> registers at kt start, reused for 16 experts
            if (ee == 0) {
#pragma unroll
                for (int mi = 0; mi < 2; ++mi)
#pragma unroll
                    for (int s = 0; s < 4; ++s)
                        areg[mi][s] = *(const s16x8*)((const char*)As + rowOffA[mi] + chunkOff[s]);
            }

            const char* Bb = (const char*)Bs[ee & 3];
            s16x8 breg[2][4];
#pragma unroll
            for (int nj = 0; nj < 2; ++nj)
#pragma unroll
                for (int s = 0; s < 4; ++s)
                    breg[nj][s] = *(const s16x8*)(Bb + rowOffB[nj] + chunkOff[s]);

            // gates -> registers (broadcast b128 reads)
            f32x4 greg[2][4];
#pragma unroll
            for (int mi = 0; mi < 2; ++mi)
#pragma unroll
                for (int gq = 0; gq < 4; ++gq)
                    greg[mi][gq] = *(const f32x4*)&Gs[ee][wm + mi * 32 + 8 * gq + 4 * hi];

#pragma unroll
            for (int nj = 0; nj < 2; ++nj) {
                __builtin_amdgcn_s_setprio(1);
                f32x16 p0 = __builtin_amdgcn_mfma_f32_32x32x16_bf16(areg[0][0], breg[nj][0], zv16, 0, 0, 0);
                f32x16 p1 = __builtin_amdgcn_mfma_f32_32x32x16_bf16(areg[1][0], breg[nj][0], zv16, 0, 0, 0);
#pragma unroll
                for (int s = 1; s < 4; ++s) {
                    p0 = __builtin_amdgcn_mfma_f32_32x32x16_bf16(areg[0][s], breg[nj][s], p0, 0, 0, 0);
                    p1 = __builtin_amdgcn_mfma_f32_32x32x16_bf16(areg[1][s], breg[nj][s], p1, 0, 0, 0);
                }
                __builtin_amdgcn_s_setprio(0);
#pragma unroll
                for (int gq = 0; gq < 4; ++gq) {
#pragma unroll
                    for (int j = 0; j < 4; ++j) {
                        acc[0][nj][4 * gq + j] += greg[0][gq][j] * p0[4 * gq + j];
                        acc[1][nj][4 * gq + j] += greg[1][gq][j] * p1[4 * gq + j];
                    }
                }
            }
        }
    }

    // epilogue: C/D layout col=lane&31, row=(reg&3)+8*(reg>>2)+4*hi
#pragma unroll
    for (int mi = 0; mi < 2; ++mi)
#pragma unroll
        for (int nj = 0; nj < 2; ++nj) {
            const int col = n0 + wn + nj * 32 + l31;
#pragma unroll
            for (int gq = 0; gq < 4; ++gq) {
                float* p = dst + (size_t)(m0 + wm + mi * 32 + 8 * gq + 4 * hi) * DIM + col;
                p[0 * DIM] = acc[mi][nj][4 * gq + 0];
                p[1 * DIM] = acc[mi][nj][4 * gq + 1];
                p[2 * DIM] = acc[mi][nj][4 * gq + 2];
                p[3 * DIM] = acc[mi][nj][4 * gq + 3];
            }
        }
}

// ---- deterministic two-phase sum: out += P (both fully written upstream) ----
__global__ __launch_bounds__(256) void k_reduce(float* __restrict__ out,
                                                const float* __restrict__ P) {
    int i = (blockIdx.x * 256 + threadIdx.x) * 4;
    float4 a = *(const float4*)(out + i);
    float4 b = *(const float4*)(P + i);
    a.x += b.x; a.y += b.y; a.z += b.z; a.w += b.w;
    *(float4*)(out + i) = a;
}

extern "C" void kernel_launch(void* const* d_in, const int* in_sizes, int n_in,
                              void* d_out, int out_size, void* d_ws, size_t ws_size,
                              hipStream_t stream) {
    const float* x  = (const float*)d_in[0];   // [8192][512]
    const float* gw = (const float*)d_in[1];   // [512][32]
    const float* gb = (const float*)d_in[2];   // [32]
    const float* w  = (const float*)d_in[3];   // [32][512][512]
    float* out = (float*)d_out;                // [8192][512] fp32

    char* ws = (char*)d_ws;
    ushort* xb = (ushort*)ws;                            //  0..8 MiB
    ushort* wt = (ushort*)(ws + (8u << 20));             //  8..24 MiB
    float*  G  = (float*)(ws + (24u << 20));             // 24..25 MiB
    float*  P  = (float*)(ws + (25u << 20));             // 25..41 MiB

    k_prep<<<dim3(2048 + TOK / 8), dim3(256), 0, stream>>>(w, wt, x, gw, gb, G, xb);
    k_moe_gemm<<<dim3(DIM / BN, TOK / BM, 2), dim3(512), 0, stream>>>(xb, wt, G, out, P);
    k_reduce<<<dim3(TOK * DIM / 1024), dim3(256), 0, stream>>>(out, P);
}

// Round 6
// 272.942 us; speedup vs baseline: 4.0476x; 4.0476x over previous
//
#include <hip/hip_runtime.h>

#define TOK 8192   // B*S
#define DIM 512    // D
#define NE  32     // experts
#define KTOT (NE * DIM)

#define BM 64
#define BN 128
#define BK 64

typedef float f32x4  __attribute__((ext_vector_type(4)));
typedef float f32x16 __attribute__((ext_vector_type(16)));
typedef short s16x8  __attribute__((ext_vector_type(8)));

typedef const void __attribute__((address_space(1)))* gp1_t;
typedef void __attribute__((address_space(3)))* lp3_t;

__device__ __forceinline__ void gl_lds16(const void* g, void* l) {
    __builtin_amdgcn_global_load_lds((gp1_t)g, (lp3_t)l, 16, 0, 0);
}

// A tile: 64 rows x 128B = 8KB; 256 thr x 16B = 4KB/round -> 2 rounds
__device__ __forceinline__ void stageA(const ushort* g, char* l) {
    gl_lds16(g,                     l);
    gl_lds16(g + (size_t)32 * DIM,  l + 4096);
}
// B tile: 128 rows x 128B = 16KB -> 4 rounds
__device__ __forceinline__ void stageB(const ushort* g, char* l) {
#pragma unroll
    for (int r = 0; r < 4; ++r)
        gl_lds16(g + (size_t)r * 32 * KTOT, l + r * 4096);
}

__device__ __forceinline__ ushort f2bf(float f) {
    unsigned u = __builtin_bit_cast(unsigned, f);
    unsigned r = (u + 0x7fffu + ((u >> 16) & 1u)) >> 16;
    return (ushort)r;
}

// ---- fused prep: blocks [0,2048) transpose+convert W; [2048,3072) gates+cvt x
__global__ __launch_bounds__(256) void k_prep(const float* __restrict__ w,
                                              ushort* __restrict__ wt,
                                              const float* __restrict__ x,
                                              const float* __restrict__ gw,
                                              const float* __restrict__ gb,
                                              float* __restrict__ G,
                                              ushort* __restrict__ xb) {
    __shared__ __align__(16) char smem[64 * 65 * 4];
    const int bx = blockIdx.x;
    const int tid = threadIdx.x;
    if (bx < 2048) {
        // ---- Wt[f][e*512+d] = bf16(w[e][d][f]), 64x64 tile ----
        float (*tile)[65] = (float(*)[65])smem;
        const int e = bx >> 6;
        const int f0 = ((bx >> 3) & 7) * 64;
        const int d0 = (bx & 7) * 64;
        const int tx = tid & 63, ty = tid >> 6;  // ty 0..3
        const float* we = w + (size_t)e * DIM * DIM;
#pragma unroll
        for (int i = ty; i < 64; i += 4)
            tile[i][tx] = we[(size_t)(d0 + i) * DIM + f0 + tx];
        __syncthreads();
#pragma unroll
        for (int i = ty; i < 64; i += 4)
            wt[(size_t)(f0 + i) * KTOT + e * DIM + d0 + tx] = f2bf(tile[tx][i]);
    } else {
        // ---- gates (8 tokens/block, shfl softmax) + x -> bf16 ----
        float* xs = (float*)smem;
        const int t0 = (bx - 2048) * 8;
        const float* xBase = x + (size_t)t0 * DIM;
#pragma unroll
        for (int k = 0; k < 4; ++k) {
            int i4 = (k * 256 + tid) * 4;
            float4 v = *(const float4*)(xBase + i4);
            xs[i4 + 0] = v.x; xs[i4 + 1] = v.y; xs[i4 + 2] = v.z; xs[i4 + 3] = v.w;
            ushort4 o;
            o.x = f2bf(v.x); o.y = f2bf(v.y); o.z = f2bf(v.z); o.w = f2bf(v.w);
            *(ushort4*)(xb + (size_t)t0 * DIM + i4) = o;
        }
        __syncthreads();
        const int tok = tid >> 5;   // 0..7
        const int e = tid & 31;
        float l = gb[e];
        const float* xr = xs + tok * DIM;
#pragma unroll 8
        for (int d = 0; d < DIM; ++d)
            l += xr[d] * gw[d * NE + e];
        float mx = l;
#pragma unroll
        for (int m = 16; m >= 1; m >>= 1) mx = fmaxf(mx, __shfl_xor(mx, m));
        float ex = expf(l - mx);
        float s = ex;
#pragma unroll
        for (int m = 16; m >= 1; m >>= 1) s += __shfl_xor(s, m);
        G[(size_t)(t0 + tok) * NE + e] = ex / s;
    }
}

// -------- main GEMM v7: all-32-expert blocks, no z-split, no reduce --------
// Ledger: v0/v1/v2/v4/v5 all ~148-155us (2-barrier structural ceiling);
// v3/v6 (counted-vmcnt) regressed/spilled. v7 keeps the PROVEN v2 sync
// (one-ahead DMA + __syncthreads) and geometry cadence (32KB B-DMA/CU/iter,
// same MFMA/CU/iter) but each block accumulates ALL 32 experts and writes
// out once: P buffer + k_reduce eliminated, A-fetch and C-writes halved.
// BM=64, BN=128, 256 thr (4 waves of 64x32), grid (4,128)=512 blk, 2/CU.
// A-frags register-resident per kt (8 areg loads per kernel, amortized /32).
// LDS: A dbuf 16KB + B dbuf 32KB + Gs 8KB = 56KB.
// C/D layout (32x32): col=lane&31, row=(reg&3)+8*(reg>>2)+4*(lane>>5).
// LDS XOR-swizzle: LDS[row][c] = Glob[row][c ^ (row&7)] (16B chunks).
__global__ __launch_bounds__(256, 2) void k_moe_gemm(const ushort* __restrict__ xb,
                                                     const ushort* __restrict__ wt,
                                                     const float* __restrict__ G,
                                                     float* __restrict__ out) {
    __shared__ __align__(16) ushort As[2][BM * BK];   // 2 x 8 KB
    __shared__ __align__(16) ushort Bs[2][BN * BK];   // 2 x 16 KB
    __shared__ float Gs[NE][BM];                      // 8 KB

    const int tid = threadIdx.x;
    const int m0 = blockIdx.y * BM;
    const int n0 = blockIdx.x * BN;

    for (int i = tid; i < NE * BM; i += 256) {
        int e = i >> 6, r = i & 63;
        Gs[e][r] = G[(size_t)(m0 + r) * NE + e];
    }

    const int lane = tid & 63;
    const int wave = tid >> 6;          // 0..3
    const int wn = wave * 32;           // 4 n-positions over BN=128
    const int l31 = lane & 31;
    const int hi = lane >> 5;           // 0..1
    const int key = l31 & 7;

    // frag read offsets: row*128 + ((2s+hi) ^ (row&7))*16   (row&7 == key)
    int chunkOff[4];
#pragma unroll
    for (int s = 0; s < 4; ++s) chunkOff[s] = ((2 * s + hi) ^ key) * 16;
    const int rowOffA0 = (l31) * 128;          // mi=0 rows 0..31
    const int rowOffA1 = (32 + l31) * 128;     // mi=1 rows 32..63
    const int rowOffB  = (wn + l31) * 128;

    // staging map: 256 thr x 16B = 4KB/round = 32 rows of 128B
    const int srow = tid >> 3;                       // 0..31
    const int scol = ((tid & 7) ^ (srow & 7)) * 8;   // swizzled global column
    const ushort* aBase = xb + (size_t)(m0 + srow) * DIM + scol;
    const ushort* bBase = wt + (size_t)(n0 + srow) * KTOT + scol;
    const int ldsOff = tid * 16;

    f32x16 zv16;
#pragma unroll
    for (int j = 0; j < 16; ++j) zv16[j] = 0.f;
    f32x16 acc[2];
    acc[0] = zv16; acc[1] = zv16;

    // prologue: stage A(kt=0) -> As[0], B(e=0,kt=0) -> Bs[0]
    stageA(aBase, (char*)As[0] + ldsOff);
    stageB(bBase, (char*)Bs[0] + ldsOff);
    __syncthreads();

#pragma unroll 1
    for (int kt = 0; kt < 8; ++kt) {
        // A fragments -> registers, reused for all 32 experts of this kt
        const char* Ab = (const char*)As[kt & 1];
        s16x8 areg[2][4];
#pragma unroll
        for (int s = 0; s < 4; ++s) {
            areg[0][s] = *(const s16x8*)(Ab + rowOffA0 + chunkOff[s]);
            areg[1][s] = *(const s16x8*)(Ab + rowOffA1 + chunkOff[s]);
        }

#pragma unroll 1
        for (int ee = 0; ee < NE; ++ee) {
            // issue next-tile DMA (one ahead); barrier at end publishes it
            const int gn = kt * NE + ee + 1;
            if (gn < 8 * NE) {
                const ushort* bN = bBase + (size_t)(gn & 31) * DIM + (gn >> 5) * BK;
                stageB(bN, (char*)Bs[gn & 1] + ldsOff);
                if (ee == NE - 1)
                    stageA(aBase + (kt + 1) * BK, (char*)As[(kt + 1) & 1] + ldsOff);
            }

            const char* Bb = (const char*)Bs[ee & 1];
            s16x8 breg[4];
#pragma unroll
            for (int s = 0; s < 4; ++s)
                breg[s] = *(const s16x8*)(Bb + rowOffB + chunkOff[s]);

            // gates -> registers (broadcast b128 reads, 2 addrs/wave)
            f32x4 greg[2][4];
#pragma unroll
            for (int mi = 0; mi < 2; ++mi)
#pragma unroll
                for (int gq = 0; gq < 4; ++gq)
                    greg[mi][gq] = *(const f32x4*)&Gs[ee][mi * 32 + 8 * gq + 4 * hi];

            f32x16 p0 = __builtin_amdgcn_mfma_f32_32x32x16_bf16(areg[0][0], breg[0], zv16, 0, 0, 0);
            f32x16 p1 = __builtin_amdgcn_mfma_f32_32x32x16_bf16(areg[1][0], breg[0], zv16, 0, 0, 0);
#pragma unroll
            for (int s = 1; s < 4; ++s) {
                p0 = __builtin_amdgcn_mfma_f32_32x32x16_bf16(areg[0][s], breg[s], p0, 0, 0, 0);
                p1 = __builtin_amdgcn_mfma_f32_32x32x16_bf16(areg[1][s], breg[s], p1, 0, 0, 0);
            }
#pragma unroll
            for (int gq = 0; gq < 4; ++gq) {
#pragma unroll
                for (int j = 0; j < 4; ++j) {
                    acc[0][4 * gq + j] += greg[0][gq][j] * p0[4 * gq + j];
                    acc[1][4 * gq + j] += greg[1][gq][j] * p1[4 * gq + j];
                }
            }
            __syncthreads();   // publishes next buffers; DMA already complete
        }
    }

    // epilogue: write out once (no P / reduce). col=lane&31 band of this wave
#pragma unroll
    for (int mi = 0; mi < 2; ++mi) {
        const int col = n0 + wn + l31;
#pragma unroll
        for (int gq = 0; gq < 4; ++gq) {
            float* p = out + (size_t)(m0 + mi * 32 + 8 * gq + 4 * hi) * DIM + col;
            p[0 * DIM] = acc[mi][4 * gq + 0];
            p[1 * DIM] = acc[mi][4 * gq + 1];
            p[2 * DIM] = acc[mi][4 * gq + 2];
            p[3 * DIM] = acc[mi][4 * gq + 3];
        }
    }
}

extern "C" void kernel_launch(void* const* d_in, const int* in_sizes, int n_in,
                              void* d_out, int out_size, void* d_ws, size_t ws_size,
                              hipStream_t stream) {
    const float* x  = (const float*)d_in[0];   // [8192][512]
    const float* gw = (const float*)d_in[1];   // [512][32]
    const float* gb = (const float*)d_in[2];   // [32]
    const float* w  = (const float*)d_in[3];   // [32][512][512]
    float* out = (float*)d_out;                // [8192][512] fp32

    char* ws = (char*)d_ws;
    ushort* xb = (ushort*)ws;                            //  0..8 MiB
    ushort* wt = (ushort*)(ws + (8u << 20));             //  8..24 MiB
    float*  G  = (float*)(ws + (24u << 20));             // 24..25 MiB

    k_prep<<<dim3(2048 + TOK / 8), dim3(256), 0, stream>>>(w, wt, x, gw, gb, G, xb);
    k_moe_gemm<<<dim3(DIM / BN, TOK / BM), dim3(256), 0, stream>>>(xb, wt, G, out);
}